// Round 6
// baseline (60.843 us; speedup 1.0000x reference)
//
#include <hip/hip_runtime.h>
#include <math.h>

#define NDET 16
#define NDIM 16

// ---- quad (4-lane) DPP helpers: pure VALU, no LDS path (R2-verbatim) -----
template<int OWNER>
__device__ __forceinline__ float bcast4f(float v) {
    constexpr int ctrl = OWNER * 0x55;  // quad_perm:[OWNER]*4
    return __int_as_float(
        __builtin_amdgcn_mov_dpp(__float_as_int(v), ctrl, 0xF, 0xF, true));
}
template<int OWNER>
__device__ __forceinline__ int bcast4i(int v) {
    constexpr int ctrl = OWNER * 0x55;
    return __builtin_amdgcn_mov_dpp(v, ctrl, 0xF, 0xF, true);
}

// ---- pivoted LU step (column K), 16x16 over a 4-lane quad (R2-verbatim) --
// lane l owns columns 4l..4l+3 as c[j][row]; all indices compile-time.
template<int K>
__device__ __forceinline__ void lu_step(float (&c)[4][16], float &prod, int &nswap) {
    constexpr int OWNER = K >> 2;   // lane owning column K
    constexpr int KC    = K & 3;    // its local column index

    if constexpr (K < 15) {
        // linear packed argmax over rows K..15 (R2-verbatim)
        unsigned key = (__float_as_uint(fabsf(c[KC][K])) & ~15u) | (unsigned)K;
        #pragma unroll
        for (int i = K + 1; i < 16; ++i) {
            unsigned ki = (__float_as_uint(fabsf(c[KC][i])) & ~15u) | (unsigned)i;
            key = key > ki ? key : ki;
        }
        const int pidx = bcast4i<OWNER>((int)(key & 15u));
        nswap += (pidx != K) ? 1 : 0;

        // row swap K <-> pidx (cndmask chain; no-op when pidx==K)
        #pragma unroll
        for (int i = K + 1; i < 16; ++i) {
            const bool msel = (i == pidx);
            #pragma unroll
            for (int j = 0; j < 4; ++j) {
                const float tk = c[j][K], ti = c[j][i];
                c[j][K] = msel ? ti : tk;
                c[j][i] = msel ? tk : ti;
            }
        }
    }

    const float pivot = bcast4f<OWNER>(c[KC][K]);
    prod *= pivot;

    if constexpr (K < 15) {
        const float rp = __builtin_amdgcn_rcpf(pivot);
        #pragma unroll
        for (int i = K + 1; i < 16; ++i) {
            const float mik = bcast4f<OWNER>(c[KC][i]) * rp;
            #pragma unroll
            for (int j = 0; j < 4; ++j)
                c[j][i] = fmaf(-mik, c[j][K], c[j][i]);
        }
    }
}

template<int K>
__device__ __forceinline__ void lu_all(float (&c)[4][16], float &prod, int &nswap) {
    lu_step<K>(c, prod, nswap);
    if constexpr (K < 15) lu_all<K + 1>(c, prod, nswap);
}

__global__ __launch_bounds__(256) void logabssumdet_kernel(
    const float* __restrict__ a,
    const float* __restrict__ b,
    const float* __restrict__ w,
    float* __restrict__ out,
    int n_samples)
{
    const int tid    = threadIdx.x;
    const int lane4  = tid & 3;
    const int group  = tid >> 2;                    // 0..63 in block
    const int mat_id = blockIdx.x * 64 + group;     // = sample*16 + det
    const int n_mats = n_samples * NDET;

    __shared__ float sx[64];
    __shared__ float ss[64];

    float x = 0.0f, sgn = 1.0f;

    if (mat_id < n_mats) {
        const float4* mbA =
            reinterpret_cast<const float4*>(a + (size_t)mat_id * (NDIM * NDIM)) + lane4;
        const float4* mbB =
            reinterpret_cast<const float4*>(b + (size_t)mat_id * (NDIM * NDIM)) + lane4;

        // hoist BOTH matrix loads; the two LU streams below are independent
        // straight-line code, so the scheduler may interleave them (2x ILP).
        float cA[4][16], cB[4][16];
        #pragma unroll
        for (int i = 0; i < 16; ++i) {
            const float4 vA = mbA[i * 4];
            const float4 vB = mbB[i * 4];
            cA[0][i] = vA.x; cA[1][i] = vA.y; cA[2][i] = vA.z; cA[3][i] = vA.w;
            cB[0][i] = vB.x; cB[1][i] = vB.y; cB[2][i] = vB.z; cB[3][i] = vB.w;
        }

        float pA = 1.0f, pB = 1.0f;
        int   nA = 0,    nB = 0;
        lu_all<0>(cA, pA, nA);      // R2-exact arithmetic, matrix A
        lu_all<0>(cB, pB, nB);      // R2-exact arithmetic, matrix B

        x = __logf(fabsf(pA)) + __logf(fabsf(pB));
        sgn = (pA < 0.0f) ? -sgn : sgn;
        sgn = (nA & 1)    ? -sgn : sgn;
        sgn = (pB < 0.0f) ? -sgn : sgn;
        sgn = (nB & 1)    ? -sgn : sgn;
    }

    if (lane4 == 0) { sx[group] = x; ss[group] = sgn; }
    __syncthreads();

    // 4 samples per block; one thread finishes each sample's 16-det LSE
    if (tid < 4) {
        const int sample = blockIdx.x * 4 + tid;
        if (sample < n_samples) {
            const int base = tid * NDET;
            float xmax = -INFINITY;
            #pragma unroll
            for (int d = 0; d < NDET; ++d) xmax = fmaxf(xmax, sx[base + d]);
            float sum = 0.0f;
            #pragma unroll
            for (int d = 0; d < NDET; ++d)
                sum += ss[base + d] * __expf(sx[base + d] - xmax) * w[d];
            out[sample] = __logf(fabsf(sum)) + xmax;
            out[n_samples + sample] = (sum > 0.0f) ? 1.0f : ((sum < 0.0f) ? -1.0f : 0.0f);
        }
    }
}

extern "C" void kernel_launch(void* const* d_in, const int* in_sizes, int n_in,
                              void* d_out, int out_size, void* d_ws, size_t ws_size,
                              hipStream_t stream)
{
    const float* a = (const float*)d_in[0];
    const float* b = (const float*)d_in[1];
    const float* w = (const float*)d_in[2];
    float* out = (float*)d_out;

    const int n_samples = in_sizes[0] / (NDET * NDIM * NDIM);
    const int blocks = (n_samples + 3) / 4;   // 4 samples (64 dets) per block
    logabssumdet_kernel<<<blocks, 256, 0, stream>>>(a, b, w, out, n_samples);
}